// Round 13
// baseline (384.473 us; speedup 1.0000x reference)
//
#include <hip/hip_runtime.h>

#define NN 20000
#define NE 320000
#define FIN 64
#define HD 256
#define NC 10
#define NG 64
#define NB ((NN + 255) / 256)   // 79 scan blocks

typedef unsigned short u16;
typedef unsigned int u32;
typedef __attribute__((ext_vector_type(8))) short short8;   // 8 bf16 (4 VGPRs)
typedef __attribute__((ext_vector_type(4))) float f32x4;    // 4 fp32 acc

__device__ __forceinline__ float bf2f(u16 u) {
    union { u32 i; float f; } v; v.i = ((u32)u) << 16; return v.f;
}
__device__ __forceinline__ u16 f2bf(float f) {
    union { float f; u32 i; } v; v.f = f;
    u32 r = v.i + 0x7fffu + ((v.i >> 16) & 1u);   // RNE
    return (u16)(r >> 16);
}

// ---------------- degree count + graph bounds (degi zeroed by memset) ------
__global__ void k_deg(const int* __restrict__ col, int* __restrict__ degi,
                      const int* __restrict__ batch, int* __restrict__ gstart) {
    int i = blockIdx.x * 256 + threadIdx.x;
    if (i < NE) atomicAdd(&degi[col[i]], 1);
    if (i < NN) {
        int b = batch[i];
        int prev = (i == 0) ? -1 : batch[i - 1];
        if (b != prev) gstart[b] = i;
    }
}

// ---------------- scan stage 1: block-local exclusive scan + block sums ----
__global__ __launch_bounds__(256) void k_scan1(const int* __restrict__ degi,
                                               int* __restrict__ rowptr,
                                               int* __restrict__ bsum) {
    int t = threadIdx.x;
    int i = blockIdx.x * 256 + t;
    int v = (i < NN) ? degi[i] : 0;
    int lane = t & 63, wid = t >> 6;
    int x = v;
#pragma unroll
    for (int off = 1; off < 64; off <<= 1) {
        int y = __shfl_up(x, off);
        if (lane >= off) x += y;
    }
    __shared__ int ws[4];
    if (lane == 63) ws[wid] = x;
    __syncthreads();
    int woff = 0;
    for (int w = 0; w < wid; ++w) woff += ws[w];
    if (i < NN) rowptr[i] = woff + x - v;
    if (t == 255) bsum[blockIdx.x] = woff + x;
}

// ---------------- scan stage 2+3 fused: fixup + cursor + dinv + u0 ---------
__global__ void k_scan3(const int* __restrict__ degi, const int* __restrict__ bsum,
                        int* __restrict__ rowptr, int* __restrict__ cursor,
                        float* __restrict__ dinv,
                        const float* __restrict__ x, u16* __restrict__ u0) {
    __shared__ int pref[NB];
    if (threadIdx.x < NB) pref[threadIdx.x] = bsum[threadIdx.x];
    __syncthreads();
    if (threadIdx.x == 0) {
        int run = 0;
        for (int k = 0; k < NB; ++k) { int t = pref[k]; pref[k] = run; run += t; }
    }
    __syncthreads();
    int i = blockIdx.x * 256 + threadIdx.x;
    if (i < NN) {
        int dg = degi[i];
        int rp = rowptr[i] + pref[i >> 8];
        rowptr[i] = rp;
        cursor[i] = rp;
        dinv[i] = rsqrtf((float)(1 + dg));
        if (i == NN - 1) rowptr[NN] = rp + dg;
    }
    if (i < NN * FIN / 4) {
        int node = i >> 4;
        float d = rsqrtf((float)(1 + degi[node]));
        float4 v = *(const float4*)&x[(size_t)i * 4];
        u32 lo = (u32)f2bf(v.x * d) | ((u32)f2bf(v.y * d) << 16);
        u32 hi = (u32)f2bf(v.z * d) | ((u32)f2bf(v.w * d) << 16);
        *(uint2*)&u0[(size_t)i * 4] = make_uint2(lo, hi);
    }
}

// ---------------- fill CSR buckets ----------------
__global__ void k_fill(const int* __restrict__ row, const int* __restrict__ col,
                       int* __restrict__ cursor, int* __restrict__ ebuf) {
    int e = blockIdx.x * 256 + threadIdx.x;
    if (e < NE) {
        int c = col[e];
        int pos = atomicAdd(&cursor[c], 1);
        ebuf[pos] = row[e];
    }
}

// ---------------- LDS-tiled transpose+cast of all 5 W ----------------
__global__ __launch_bounds__(256) void k_trans(const float* __restrict__ W0, const float* __restrict__ W1,
                                               const float* __restrict__ W2, const float* __restrict__ W3,
                                               const float* __restrict__ W4,
                                               u16* __restrict__ T0, u16* __restrict__ T1,
                                               u16* __restrict__ T2, u16* __restrict__ T3,
                                               u16* __restrict__ T4) {
    int l = blockIdx.z;
    const float* W = (l == 0) ? W0 : (l == 1) ? W1 : (l == 2) ? W2 : (l == 3) ? W3 : W4;
    u16* T = (l == 0) ? T0 : (l == 1) ? T1 : (l == 2) ? T2 : (l == 3) ? T3 : T4;
    int K = (l == 0) ? FIN : HD;
    int k0 = blockIdx.x * 32;
    if (k0 >= K) return;
    int n0 = blockIdx.y * 32;
    __shared__ float tile[32][33];
    int tx = threadIdx.x & 31, ty = threadIdx.x >> 5;
#pragma unroll
    for (int r = 0; r < 32; r += 8)
        tile[ty + r][tx] = W[(size_t)(k0 + ty + r) * HD + n0 + tx];
    __syncthreads();
#pragma unroll
    for (int r = 0; r < 32; r += 8)
        T[(size_t)(n0 + ty + r) * K + k0 + tx] = f2bf(tile[tx][ty + r]);
}

// ---------------- gather 64-wide (layer 1): 16 edges/iter in flight --------
__global__ __launch_bounds__(256) void k_gather64(const u16* __restrict__ U,
                                                  const int* __restrict__ rowptr,
                                                  const int* __restrict__ ebuf,
                                                  const float* __restrict__ dinv,
                                                  u16* __restrict__ Z) {
    int n = blockIdx.x * 4 + (threadIdx.x >> 6);
    if (n >= NN) return;
    int lane = threadIdx.x & 63;
    int grp = lane >> 3;            // 0..7
    int seg = lane & 7;             // 16-B feature segment
    int s = rowptr[n], e = rowptr[n + 1];
    float acc[8];
    if (grp == 0) {
        uint4 v = *(const uint4*)&U[(size_t)n * FIN + seg * 8];
        acc[0] = bf2f((u16)(v.x & 0xffff)); acc[1] = bf2f((u16)(v.x >> 16));
        acc[2] = bf2f((u16)(v.y & 0xffff)); acc[3] = bf2f((u16)(v.y >> 16));
        acc[4] = bf2f((u16)(v.z & 0xffff)); acc[5] = bf2f((u16)(v.z >> 16));
        acc[6] = bf2f((u16)(v.w & 0xffff)); acc[7] = bf2f((u16)(v.w >> 16));
    } else {
#pragma unroll
        for (int k = 0; k < 8; ++k) acc[k] = 0.f;
    }
    for (int j = s; j < e; j += 16) {
        int i0 = j + grp, i1 = j + 8 + grp;
        int r0 = (i0 < e) ? ebuf[i0] : -1;
        int r1 = (i1 < e) ? ebuf[i1] : -1;
        uint4 v0 = *(const uint4*)&U[(size_t)max(r0, 0) * FIN + seg * 8];
        uint4 v1 = *(const uint4*)&U[(size_t)max(r1, 0) * FIN + seg * 8];
        if (r0 < 0) v0 = make_uint4(0u, 0u, 0u, 0u);
        if (r1 < 0) v1 = make_uint4(0u, 0u, 0u, 0u);
        acc[0] += bf2f((u16)(v0.x & 0xffff)); acc[1] += bf2f((u16)(v0.x >> 16));
        acc[2] += bf2f((u16)(v0.y & 0xffff)); acc[3] += bf2f((u16)(v0.y >> 16));
        acc[4] += bf2f((u16)(v0.z & 0xffff)); acc[5] += bf2f((u16)(v0.z >> 16));
        acc[6] += bf2f((u16)(v0.w & 0xffff)); acc[7] += bf2f((u16)(v0.w >> 16));
        acc[0] += bf2f((u16)(v1.x & 0xffff)); acc[1] += bf2f((u16)(v1.x >> 16));
        acc[2] += bf2f((u16)(v1.y & 0xffff)); acc[3] += bf2f((u16)(v1.y >> 16));
        acc[4] += bf2f((u16)(v1.z & 0xffff)); acc[5] += bf2f((u16)(v1.z >> 16));
        acc[6] += bf2f((u16)(v1.w & 0xffff)); acc[7] += bf2f((u16)(v1.w >> 16));
    }
#pragma unroll
    for (int off = 8; off < 64; off <<= 1)
#pragma unroll
        for (int k = 0; k < 8; ++k) acc[k] += __shfl_xor(acc[k], off);
    if (grp == 0) {
        float d = dinv[n];
        uint4 o;
        o.x = (u32)f2bf(acc[0] * d) | ((u32)f2bf(acc[1] * d) << 16);
        o.y = (u32)f2bf(acc[2] * d) | ((u32)f2bf(acc[3] * d) << 16);
        o.z = (u32)f2bf(acc[4] * d) | ((u32)f2bf(acc[5] * d) << 16);
        o.w = (u32)f2bf(acc[6] * d) | ((u32)f2bf(acc[7] * d) << 16);
        *(uint4*)&Z[(size_t)n * FIN + seg * 8] = o;
    }
}

// ---------------- MFMA matmul (r10 LDS version) — used for layer 1 ---------
__global__ __launch_bounds__(256) void k_mm(const u16* __restrict__ A,
                                            const u16* __restrict__ Wt,
                                            const float* __restrict__ bias,
                                            const float* __restrict__ dinv,
                                            u16* __restrict__ O,
                                            int K, int scaleOut) {
    __shared__ u16 Asm[64][40];
    __shared__ u16 Bsm[256][40];
    __shared__ float bs[HD];
    const int m0 = blockIdx.x * 64;
    const int t = threadIdx.x;
    const int wave = t >> 6;
    const int lane = t & 63;
    const int quad = lane >> 4;
    const int l16 = lane & 15;
    const int n0 = wave * 64;
    bs[t] = bias[t];

    f32x4 acc[4][4];
#pragma unroll
    for (int i = 0; i < 4; ++i)
#pragma unroll
        for (int j = 0; j < 4; ++j) acc[i][j] = (f32x4){0.f, 0.f, 0.f, 0.f};

    for (int k0 = 0; k0 < K; k0 += 32) {
        {
            int row = t >> 2, seg = t & 3;
            int gm = m0 + row;
            float4 v = make_float4(0.f, 0.f, 0.f, 0.f);
            if (gm < NN) v = *(const float4*)&A[(size_t)gm * K + k0 + seg * 8];
            *(float4*)&Asm[row][seg * 8] = v;
        }
        {
#pragma unroll
            for (int j = 0; j < 4; ++j) {
                float4 v = *(const float4*)&Wt[(size_t)t * K + k0 + j * 8];
                *(float4*)&Bsm[t][j * 8] = v;
            }
        }
        __syncthreads();
        short8 a[4], b[4];
#pragma unroll
        for (int i = 0; i < 4; ++i) a[i] = *(const short8*)&Asm[i * 16 + l16][quad * 8];
#pragma unroll
        for (int j = 0; j < 4; ++j) b[j] = *(const short8*)&Bsm[n0 + j * 16 + l16][quad * 8];
#pragma unroll
        for (int i = 0; i < 4; ++i)
#pragma unroll
            for (int j = 0; j < 4; ++j)
                acc[i][j] = __builtin_amdgcn_mfma_f32_16x16x32_bf16(a[i], b[j], acc[i][j], 0, 0, 0);
        __syncthreads();
    }
#pragma unroll
    for (int i = 0; i < 4; ++i) {
#pragma unroll
        for (int r = 0; r < 4; ++r) {
            int m = m0 + i * 16 + quad * 4 + r;
            if (m >= NN) continue;
            float d = scaleOut ? dinv[m] : 1.0f;
#pragma unroll
            for (int j = 0; j < 4; ++j) {
                int n = n0 + j * 16 + l16;
                float val = fmaxf(acc[i][j][r] + bs[n], 0.f) * d;
                O[(size_t)m * HD + n] = f2bf(val);
            }
        }
    }
}

// ---------------- fused layer (K=256): gather -> Zsm(LDS) -> MFMA ----------
// LDS = Zsm only (33 KB) -> 4 blocks/CU, 16 waves/CU (fixes r9's occupancy).
// mm phase: A fragments from Zsm (ds_read_b128), B fragments DIRECT from
// global Wt (L2-hot 128 KB); no Bsm, no bias LDS, no k-loop barriers.
__global__ __launch_bounds__(256) void k_flayer(const u16* __restrict__ U,
                                                const int* __restrict__ rowptr,
                                                const int* __restrict__ ebuf,
                                                const float* __restrict__ dinv,
                                                const u16* __restrict__ Wt,
                                                const float* __restrict__ bias,
                                                u16* __restrict__ O,
                                                int scaleOut) {
    __shared__ u16 Zsm[64][264];   // 33 KB, pad 8
    const int m0 = blockIdx.x * 64;
    const int t = threadIdx.x;
    const int wave = t >> 6;
    const int lane = t & 63;

    // ---- phase 1: each wave gathers 16 nodes (full 256-wide, 2 half-lanes)
    const int half = lane >> 5;
    const int seg = lane & 31;
    for (int ni = 0; ni < 16; ++ni) {
        int zrow = wave * 16 + ni;
        int n = m0 + zrow;
        if (n < NN) {
            int s = rowptr[n], e = rowptr[n + 1];
            float acc[8];
            if (half == 0) {
                uint4 v = *(const uint4*)&U[(size_t)n * HD + seg * 8];
                acc[0] = bf2f((u16)(v.x & 0xffff)); acc[1] = bf2f((u16)(v.x >> 16));
                acc[2] = bf2f((u16)(v.y & 0xffff)); acc[3] = bf2f((u16)(v.y >> 16));
                acc[4] = bf2f((u16)(v.z & 0xffff)); acc[5] = bf2f((u16)(v.z >> 16));
                acc[6] = bf2f((u16)(v.w & 0xffff)); acc[7] = bf2f((u16)(v.w >> 16));
            } else {
#pragma unroll
                for (int k = 0; k < 8; ++k) acc[k] = 0.f;
            }
            for (int j = s; j < e; j += 32) {
                int idx = j + lane;
                int myid = (lane < 32 && idx < e) ? ebuf[idx] : -1;
                uint4 v[16];
#pragma unroll
                for (int k = 0; k < 16; ++k) {
                    int r = __shfl(myid, 2 * k + half);
                    uint4 tv = *(const uint4*)&U[(size_t)max(r, 0) * HD + seg * 8];
                    if (r < 0) tv = make_uint4(0u, 0u, 0u, 0u);
                    v[k] = tv;
                }
#pragma unroll
                for (int k = 0; k < 16; ++k) {
                    acc[0] += bf2f((u16)(v[k].x & 0xffff)); acc[1] += bf2f((u16)(v[k].x >> 16));
                    acc[2] += bf2f((u16)(v[k].y & 0xffff)); acc[3] += bf2f((u16)(v[k].y >> 16));
                    acc[4] += bf2f((u16)(v[k].z & 0xffff)); acc[5] += bf2f((u16)(v[k].z >> 16));
                    acc[6] += bf2f((u16)(v[k].w & 0xffff)); acc[7] += bf2f((u16)(v[k].w >> 16));
                }
            }
#pragma unroll
            for (int k = 0; k < 8; ++k) acc[k] += __shfl_xor(acc[k], 32);
            if (half == 0) {
                float d = dinv[n];
                uint4 o;
                o.x = (u32)f2bf(acc[0] * d) | ((u32)f2bf(acc[1] * d) << 16);
                o.y = (u32)f2bf(acc[2] * d) | ((u32)f2bf(acc[3] * d) << 16);
                o.z = (u32)f2bf(acc[4] * d) | ((u32)f2bf(acc[5] * d) << 16);
                o.w = (u32)f2bf(acc[6] * d) | ((u32)f2bf(acc[7] * d) << 16);
                *(uint4*)&Zsm[zrow][seg * 8] = o;
            }
        } else if (half == 0) {
            *(uint4*)&Zsm[zrow][seg * 8] = make_uint4(0u, 0u, 0u, 0u);
        }
    }
    __syncthreads();

    // ---- phase 2: MFMA, A from Zsm, B direct from global Wt ----
    const int quad = lane >> 4;
    const int l16 = lane & 15;
    const int n0 = wave * 64;
    const u16* Bb = Wt + (size_t)(n0 + l16) * HD + quad * 8;

    f32x4 acc2[4][4];
#pragma unroll
    for (int i = 0; i < 4; ++i)
#pragma unroll
        for (int j = 0; j < 4; ++j) acc2[i][j] = (f32x4){0.f, 0.f, 0.f, 0.f};

#pragma unroll 2
    for (int k0 = 0; k0 < HD; k0 += 32) {
        short8 a[4], b[4];
#pragma unroll
        for (int i = 0; i < 4; ++i) a[i] = *(const short8*)&Zsm[i * 16 + l16][k0 + quad * 8];
#pragma unroll
        for (int j = 0; j < 4; ++j) b[j] = *(const short8*)&Bb[(size_t)j * 16 * HD + k0];
#pragma unroll
        for (int i = 0; i < 4; ++i)
#pragma unroll
            for (int j = 0; j < 4; ++j)
                acc2[i][j] = __builtin_amdgcn_mfma_f32_16x16x32_bf16(a[i], b[j], acc2[i][j], 0, 0, 0);
    }

    float bw[4];
#pragma unroll
    for (int j = 0; j < 4; ++j) bw[j] = bias[n0 + j * 16 + l16];
#pragma unroll
    for (int i = 0; i < 4; ++i) {
#pragma unroll
        for (int r = 0; r < 4; ++r) {
            int m = m0 + i * 16 + quad * 4 + r;
            if (m >= NN) continue;
            float d = scaleOut ? dinv[m] : 1.0f;
#pragma unroll
            for (int j = 0; j < 4; ++j) {
                int n = n0 + j * 16 + l16;
                float val = fmaxf(acc2[i][j][r] + bw[j], 0.f) * d;
                O[(size_t)m * HD + n] = f2bf(val);
            }
        }
    }
}

// ---------------- fused pool + head ----------------
__global__ __launch_bounds__(256) void k_poolout(const u16* __restrict__ h,
                                                 const int* __restrict__ gstart,
                                                 const float* __restrict__ Wout,
                                                 const float* __restrict__ bout,
                                                 float* __restrict__ out) {
    int g = blockIdx.x;
    int t = threadIdx.x;
    __shared__ float pooled[HD];
    __shared__ float part[NC][16];
    __shared__ int s_se[2];
    if (t == 0) {
        int st = gstart[g];
        int en = NN;
        for (int gg = g + 1; gg < NG; ++gg) en = min(en, gstart[gg]);
        s_se[0] = st; s_se[1] = en;
    }
    __syncthreads();
    int st = s_se[0], en = s_se[1];
    float a0 = 0.f, a1 = 0.f, a2 = 0.f, a3 = 0.f;
    int n = st;
    for (; n + 4 <= en; n += 4) {
        a0 += bf2f(h[(size_t)n * HD + t]);
        a1 += bf2f(h[(size_t)(n + 1) * HD + t]);
        a2 += bf2f(h[(size_t)(n + 2) * HD + t]);
        a3 += bf2f(h[(size_t)(n + 3) * HD + t]);
    }
    for (; n < en; ++n) a0 += bf2f(h[(size_t)n * HD + t]);
    float inv = 1.0f / (float)max(en - st, 1);
    pooled[t] = (a0 + a1 + a2 + a3) * inv;
    __syncthreads();
    if (t < NC * 16) {
        int c = t >> 4, l16 = t & 15;
        float s = 0.f;
        for (int f = l16; f < HD; f += 16)
            s = fmaf(pooled[f], Wout[(size_t)f * NC + c], s);
        part[c][l16] = s;
    }
    __syncthreads();
    if (t < NC) {
        float s = 0.f;
#pragma unroll
        for (int k = 0; k < 16; ++k) s += part[t][k];
        out[(size_t)g * NC + t] = s + bout[t];
    }
}

extern "C" void kernel_launch(void* const* d_in, const int* in_sizes, int n_in,
                              void* d_out, int out_size, void* d_ws, size_t ws_size,
                              hipStream_t stream) {
    const float* x     = (const float*)d_in[0];
    const int*   ei    = (const int*)d_in[1];
    const int*   batch = (const int*)d_in[2];
    const float* Wl[5] = {(const float*)d_in[3], (const float*)d_in[5], (const float*)d_in[7],
                          (const float*)d_in[9], (const float*)d_in[11]};
    const float* bl[5] = {(const float*)d_in[4], (const float*)d_in[6], (const float*)d_in[8],
                          (const float*)d_in[10], (const float*)d_in[12]};
    const float* Wout = (const float*)d_in[13];
    const float* bout = (const float*)d_in[14];
    float* out = (float*)d_out;

    const int* row = ei;
    const int* col = ei + NE;

    char* p = (char*)d_ws;
    auto take = [&](size_t bytes) { char* q = p; p += (bytes + 255) & ~(size_t)255; return q; };
    float* dinv   = (float*)take(NN * 4);
    int*   degi   = (int*)take(NN * 4);
    int*   rowptr = (int*)take((NN + 1) * 4);
    int*   cursor = (int*)take(NN * 4);
    int*   bsum   = (int*)take(NB * 4);
    int*   ebuf   = (int*)take(NE * 4);
    int*   gstart = (int*)take(NG * 4);
    u16*   Wt[5];
    for (int l = 0; l < 5; ++l) Wt[l] = (u16*)take((size_t)HD * HD * 2);
    u16*   B1     = (u16*)take((size_t)NN * HD * 2);
    u16*   B2     = (u16*)take((size_t)NN * HD * 2);

    hipMemsetAsync(degi, 0, NN * 4, stream);
    hipMemsetAsync(gstart, 0x7F, NG * 4, stream);   // sentinel > NN
    k_deg<<<(NE + 255) / 256, 256, 0, stream>>>(col, degi, batch, gstart);
    k_scan1<<<NB, 256, 0, stream>>>(degi, rowptr, bsum);
    k_scan3<<<(NN * FIN / 4 + 255) / 256, 256, 0, stream>>>(degi, bsum, rowptr, cursor, dinv, x, B1);
    k_fill<<<(NE + 255) / 256, 256, 0, stream>>>(row, col, cursor, ebuf);
    dim3 tGrid(8, 8, 5);
    k_trans<<<tGrid, 256, 0, stream>>>(Wl[0], Wl[1], Wl[2], Wl[3], Wl[4],
                                       Wt[0], Wt[1], Wt[2], Wt[3], Wt[4]);

    const int grid = (NN + 63) / 64;
    // layer 1: split (64-wide aggregation + r10 LDS mm)
    k_gather64<<<(NN + 3) / 4, 256, 0, stream>>>(B1, rowptr, ebuf, dinv, B2);
    k_mm<<<grid, 256, 0, stream>>>(B2, Wt[0], bl[0], dinv, B1, FIN, 1);
    // layers 2..5: fused gather+MFMA, ping-pong B1 <-> B2
    k_flayer<<<grid, 256, 0, stream>>>(B1, rowptr, ebuf, dinv, Wt[1], bl[1], B2, 1);
    k_flayer<<<grid, 256, 0, stream>>>(B2, rowptr, ebuf, dinv, Wt[2], bl[2], B1, 1);
    k_flayer<<<grid, 256, 0, stream>>>(B1, rowptr, ebuf, dinv, Wt[3], bl[3], B2, 1);
    k_flayer<<<grid, 256, 0, stream>>>(B2, rowptr, ebuf, dinv, Wt[4], bl[4], B1, 0);

    k_poolout<<<NG, 256, 0, stream>>>(B1, gstart, Wout, bout, out);
}

// Round 14
// 375.756 us; speedup vs baseline: 1.0232x; 1.0232x over previous
//
#include <hip/hip_runtime.h>

#define NN 20000
#define NE 320000
#define FIN 64
#define HD 256
#define NC 10
#define NG 64
#define NB ((NN + 255) / 256)   // 79 scan blocks

typedef unsigned short u16;
typedef unsigned int u32;
typedef __attribute__((ext_vector_type(8))) short short8;   // 8 bf16 (4 VGPRs)
typedef __attribute__((ext_vector_type(4))) float f32x4;    // 4 fp32 acc

__device__ __forceinline__ float bf2f(u16 u) {
    union { u32 i; float f; } v; v.i = ((u32)u) << 16; return v.f;
}
__device__ __forceinline__ u16 f2bf(float f) {
    union { float f; u32 i; } v; v.f = f;
    u32 r = v.i + 0x7fffu + ((v.i >> 16) & 1u);   // RNE
    return (u16)(r >> 16);
}

// ---------------- degree count + graph bounds (degi zeroed by memset) ------
__global__ void k_deg(const int* __restrict__ col, int* __restrict__ degi,
                      const int* __restrict__ batch, int* __restrict__ gstart) {
    int i = blockIdx.x * 256 + threadIdx.x;
    if (i < NE) atomicAdd(&degi[col[i]], 1);
    if (i < NN) {
        int b = batch[i];
        int prev = (i == 0) ? -1 : batch[i - 1];
        if (b != prev) gstart[b] = i;
    }
}

// ---------------- scan stage 1: block-local exclusive scan + block sums ----
__global__ __launch_bounds__(256) void k_scan1(const int* __restrict__ degi,
                                               int* __restrict__ rowptr,
                                               int* __restrict__ bsum) {
    int t = threadIdx.x;
    int i = blockIdx.x * 256 + t;
    int v = (i < NN) ? degi[i] : 0;
    int lane = t & 63, wid = t >> 6;
    int x = v;
#pragma unroll
    for (int off = 1; off < 64; off <<= 1) {
        int y = __shfl_up(x, off);
        if (lane >= off) x += y;
    }
    __shared__ int ws[4];
    if (lane == 63) ws[wid] = x;
    __syncthreads();
    int woff = 0;
    for (int w = 0; w < wid; ++w) woff += ws[w];
    if (i < NN) rowptr[i] = woff + x - v;
    if (t == 255) bsum[blockIdx.x] = woff + x;
}

// ---------------- scan stage 2+3 fused: fixup + cursor + dinv + u0 ---------
__global__ void k_scan3(const int* __restrict__ degi, const int* __restrict__ bsum,
                        int* __restrict__ rowptr, int* __restrict__ cursor,
                        float* __restrict__ dinv,
                        const float* __restrict__ x, u16* __restrict__ u0) {
    __shared__ int pref[NB];
    if (threadIdx.x < NB) pref[threadIdx.x] = bsum[threadIdx.x];
    __syncthreads();
    if (threadIdx.x == 0) {
        int run = 0;
        for (int k = 0; k < NB; ++k) { int t = pref[k]; pref[k] = run; run += t; }
    }
    __syncthreads();
    int i = blockIdx.x * 256 + threadIdx.x;
    if (i < NN) {
        int dg = degi[i];
        int rp = rowptr[i] + pref[i >> 8];
        rowptr[i] = rp;
        cursor[i] = rp;
        dinv[i] = rsqrtf((float)(1 + dg));
        if (i == NN - 1) rowptr[NN] = rp + dg;
    }
    if (i < NN * FIN / 4) {
        int node = i >> 4;
        float d = rsqrtf((float)(1 + degi[node]));
        float4 v = *(const float4*)&x[(size_t)i * 4];
        u32 lo = (u32)f2bf(v.x * d) | ((u32)f2bf(v.y * d) << 16);
        u32 hi = (u32)f2bf(v.z * d) | ((u32)f2bf(v.w * d) << 16);
        *(uint2*)&u0[(size_t)i * 4] = make_uint2(lo, hi);
    }
}

// ---------------- fill CSR buckets ----------------
__global__ void k_fill(const int* __restrict__ row, const int* __restrict__ col,
                       int* __restrict__ cursor, int* __restrict__ ebuf) {
    int e = blockIdx.x * 256 + threadIdx.x;
    if (e < NE) {
        int c = col[e];
        int pos = atomicAdd(&cursor[c], 1);
        ebuf[pos] = row[e];
    }
}

// ---------------- LDS-tiled transpose+cast of all 5 W ----------------
__global__ __launch_bounds__(256) void k_trans(const float* __restrict__ W0, const float* __restrict__ W1,
                                               const float* __restrict__ W2, const float* __restrict__ W3,
                                               const float* __restrict__ W4,
                                               u16* __restrict__ T0, u16* __restrict__ T1,
                                               u16* __restrict__ T2, u16* __restrict__ T3,
                                               u16* __restrict__ T4) {
    int l = blockIdx.z;
    const float* W = (l == 0) ? W0 : (l == 1) ? W1 : (l == 2) ? W2 : (l == 3) ? W3 : W4;
    u16* T = (l == 0) ? T0 : (l == 1) ? T1 : (l == 2) ? T2 : (l == 3) ? T3 : T4;
    int K = (l == 0) ? FIN : HD;
    int k0 = blockIdx.x * 32;
    if (k0 >= K) return;
    int n0 = blockIdx.y * 32;
    __shared__ float tile[32][33];
    int tx = threadIdx.x & 31, ty = threadIdx.x >> 5;
#pragma unroll
    for (int r = 0; r < 32; r += 8)
        tile[ty + r][tx] = W[(size_t)(k0 + ty + r) * HD + n0 + tx];
    __syncthreads();
#pragma unroll
    for (int r = 0; r < 32; r += 8)
        T[(size_t)(n0 + ty + r) * K + k0 + tx] = f2bf(tile[tx][ty + r]);
}

// ---------------- gather 64-wide (layer 1): 16 edges/iter in flight --------
__global__ __launch_bounds__(256) void k_gather64(const u16* __restrict__ U,
                                                  const int* __restrict__ rowptr,
                                                  const int* __restrict__ ebuf,
                                                  const float* __restrict__ dinv,
                                                  u16* __restrict__ Z) {
    int n = blockIdx.x * 4 + (threadIdx.x >> 6);
    if (n >= NN) return;
    int lane = threadIdx.x & 63;
    int grp = lane >> 3;            // 0..7
    int seg = lane & 7;             // 16-B feature segment
    int s = rowptr[n], e = rowptr[n + 1];
    float acc[8];
    if (grp == 0) {
        uint4 v = *(const uint4*)&U[(size_t)n * FIN + seg * 8];
        acc[0] = bf2f((u16)(v.x & 0xffff)); acc[1] = bf2f((u16)(v.x >> 16));
        acc[2] = bf2f((u16)(v.y & 0xffff)); acc[3] = bf2f((u16)(v.y >> 16));
        acc[4] = bf2f((u16)(v.z & 0xffff)); acc[5] = bf2f((u16)(v.z >> 16));
        acc[6] = bf2f((u16)(v.w & 0xffff)); acc[7] = bf2f((u16)(v.w >> 16));
    } else {
#pragma unroll
        for (int k = 0; k < 8; ++k) acc[k] = 0.f;
    }
    for (int j = s; j < e; j += 16) {
        int i0 = j + grp, i1 = j + 8 + grp;
        int r0 = (i0 < e) ? ebuf[i0] : -1;
        int r1 = (i1 < e) ? ebuf[i1] : -1;
        uint4 v0 = *(const uint4*)&U[(size_t)max(r0, 0) * FIN + seg * 8];
        uint4 v1 = *(const uint4*)&U[(size_t)max(r1, 0) * FIN + seg * 8];
        if (r0 < 0) v0 = make_uint4(0u, 0u, 0u, 0u);
        if (r1 < 0) v1 = make_uint4(0u, 0u, 0u, 0u);
        acc[0] += bf2f((u16)(v0.x & 0xffff)); acc[1] += bf2f((u16)(v0.x >> 16));
        acc[2] += bf2f((u16)(v0.y & 0xffff)); acc[3] += bf2f((u16)(v0.y >> 16));
        acc[4] += bf2f((u16)(v0.z & 0xffff)); acc[5] += bf2f((u16)(v0.z >> 16));
        acc[6] += bf2f((u16)(v0.w & 0xffff)); acc[7] += bf2f((u16)(v0.w >> 16));
        acc[0] += bf2f((u16)(v1.x & 0xffff)); acc[1] += bf2f((u16)(v1.x >> 16));
        acc[2] += bf2f((u16)(v1.y & 0xffff)); acc[3] += bf2f((u16)(v1.y >> 16));
        acc[4] += bf2f((u16)(v1.z & 0xffff)); acc[5] += bf2f((u16)(v1.z >> 16));
        acc[6] += bf2f((u16)(v1.w & 0xffff)); acc[7] += bf2f((u16)(v1.w >> 16));
    }
#pragma unroll
    for (int off = 8; off < 64; off <<= 1)
#pragma unroll
        for (int k = 0; k < 8; ++k) acc[k] += __shfl_xor(acc[k], off);
    if (grp == 0) {
        float d = dinv[n];
        uint4 o;
        o.x = (u32)f2bf(acc[0] * d) | ((u32)f2bf(acc[1] * d) << 16);
        o.y = (u32)f2bf(acc[2] * d) | ((u32)f2bf(acc[3] * d) << 16);
        o.z = (u32)f2bf(acc[4] * d) | ((u32)f2bf(acc[5] * d) << 16);
        o.w = (u32)f2bf(acc[6] * d) | ((u32)f2bf(acc[7] * d) << 16);
        *(uint4*)&Z[(size_t)n * FIN + seg * 8] = o;
    }
}

// ---------------- MFMA matmul (r10 LDS version) — used for layer 1 ---------
__global__ __launch_bounds__(256) void k_mm(const u16* __restrict__ A,
                                            const u16* __restrict__ Wt,
                                            const float* __restrict__ bias,
                                            const float* __restrict__ dinv,
                                            u16* __restrict__ O,
                                            int K, int scaleOut) {
    __shared__ u16 Asm[64][40];
    __shared__ u16 Bsm[256][40];
    __shared__ float bs[HD];
    const int m0 = blockIdx.x * 64;
    const int t = threadIdx.x;
    const int wave = t >> 6;
    const int lane = t & 63;
    const int quad = lane >> 4;
    const int l16 = lane & 15;
    const int n0 = wave * 64;
    bs[t] = bias[t];

    f32x4 acc[4][4];
#pragma unroll
    for (int i = 0; i < 4; ++i)
#pragma unroll
        for (int j = 0; j < 4; ++j) acc[i][j] = (f32x4){0.f, 0.f, 0.f, 0.f};

    for (int k0 = 0; k0 < K; k0 += 32) {
        {
            int row = t >> 2, seg = t & 3;
            int gm = m0 + row;
            float4 v = make_float4(0.f, 0.f, 0.f, 0.f);
            if (gm < NN) v = *(const float4*)&A[(size_t)gm * K + k0 + seg * 8];
            *(float4*)&Asm[row][seg * 8] = v;
        }
        {
#pragma unroll
            for (int j = 0; j < 4; ++j) {
                float4 v = *(const float4*)&Wt[(size_t)t * K + k0 + j * 8];
                *(float4*)&Bsm[t][j * 8] = v;
            }
        }
        __syncthreads();
        short8 a[4], b[4];
#pragma unroll
        for (int i = 0; i < 4; ++i) a[i] = *(const short8*)&Asm[i * 16 + l16][quad * 8];
#pragma unroll
        for (int j = 0; j < 4; ++j) b[j] = *(const short8*)&Bsm[n0 + j * 16 + l16][quad * 8];
#pragma unroll
        for (int i = 0; i < 4; ++i)
#pragma unroll
            for (int j = 0; j < 4; ++j)
                acc[i][j] = __builtin_amdgcn_mfma_f32_16x16x32_bf16(a[i], b[j], acc[i][j], 0, 0, 0);
        __syncthreads();
    }
#pragma unroll
    for (int i = 0; i < 4; ++i) {
#pragma unroll
        for (int r = 0; r < 4; ++r) {
            int m = m0 + i * 16 + quad * 4 + r;
            if (m >= NN) continue;
            float d = scaleOut ? dinv[m] : 1.0f;
#pragma unroll
            for (int j = 0; j < 4; ++j) {
                int n = n0 + j * 16 + l16;
                float val = fmaxf(acc[i][j][r] + bs[n], 0.f) * d;
                O[(size_t)m * HD + n] = f2bf(val);
            }
        }
    }
}

// ---------------- fused layer, M=16 tile: gather -> Zsm(8.5KB) -> MFMA -----
// Grid = NN/16 = 1250 blocks (~5 blocks/CU) so the latency-bound gather phase
// keeps standalone-class wave parallelism (r9/r13 failed at 313 blocks).
// Phase 2: A-frag broadcast from Zsm; B-frags DIRECT from L2-hot global Wt.
// NN % 16 == 0 -> no tail bounds checks.
__global__ __launch_bounds__(256) void k_flayer16(const u16* __restrict__ U,
                                                  const int* __restrict__ rowptr,
                                                  const int* __restrict__ ebuf,
                                                  const float* __restrict__ dinv,
                                                  const u16* __restrict__ Wt,
                                                  const float* __restrict__ bias,
                                                  u16* __restrict__ O,
                                                  int scaleOut) {
    __shared__ u16 Zsm[16][264];   // 8.5 KB, pad 8
    const int m0 = blockIdx.x * 16;
    const int t = threadIdx.x;
    const int wave = t >> 6;
    const int lane = t & 63;

    // ---- phase 1: each wave gathers 4 nodes (2 half-lanes, 16 loads in flight)
    const int half = lane >> 5;
    const int seg = lane & 31;
#pragma unroll
    for (int ni = 0; ni < 4; ++ni) {
        int zrow = wave * 4 + ni;
        int n = m0 + zrow;
        int s = rowptr[n], e = rowptr[n + 1];
        float acc[8];
        if (half == 0) {
            uint4 v = *(const uint4*)&U[(size_t)n * HD + seg * 8];
            acc[0] = bf2f((u16)(v.x & 0xffff)); acc[1] = bf2f((u16)(v.x >> 16));
            acc[2] = bf2f((u16)(v.y & 0xffff)); acc[3] = bf2f((u16)(v.y >> 16));
            acc[4] = bf2f((u16)(v.z & 0xffff)); acc[5] = bf2f((u16)(v.z >> 16));
            acc[6] = bf2f((u16)(v.w & 0xffff)); acc[7] = bf2f((u16)(v.w >> 16));
        } else {
#pragma unroll
            for (int k = 0; k < 8; ++k) acc[k] = 0.f;
        }
        for (int j = s; j < e; j += 32) {
            int idx = j + lane;
            int myid = (lane < 32 && idx < e) ? ebuf[idx] : -1;
            uint4 v[16];
#pragma unroll
            for (int k = 0; k < 16; ++k) {
                int r = __shfl(myid, 2 * k + half);
                uint4 tv = *(const uint4*)&U[(size_t)max(r, 0) * HD + seg * 8];
                if (r < 0) tv = make_uint4(0u, 0u, 0u, 0u);
                v[k] = tv;
            }
#pragma unroll
            for (int k = 0; k < 16; ++k) {
                acc[0] += bf2f((u16)(v[k].x & 0xffff)); acc[1] += bf2f((u16)(v[k].x >> 16));
                acc[2] += bf2f((u16)(v[k].y & 0xffff)); acc[3] += bf2f((u16)(v[k].y >> 16));
                acc[4] += bf2f((u16)(v[k].z & 0xffff)); acc[5] += bf2f((u16)(v[k].z >> 16));
                acc[6] += bf2f((u16)(v[k].w & 0xffff)); acc[7] += bf2f((u16)(v[k].w >> 16));
            }
        }
#pragma unroll
        for (int k = 0; k < 8; ++k) acc[k] += __shfl_xor(acc[k], 32);
        if (half == 0) {
            float d = dinv[n];
            uint4 o;
            o.x = (u32)f2bf(acc[0] * d) | ((u32)f2bf(acc[1] * d) << 16);
            o.y = (u32)f2bf(acc[2] * d) | ((u32)f2bf(acc[3] * d) << 16);
            o.z = (u32)f2bf(acc[4] * d) | ((u32)f2bf(acc[5] * d) << 16);
            o.w = (u32)f2bf(acc[6] * d) | ((u32)f2bf(acc[7] * d) << 16);
            *(uint4*)&Zsm[zrow][seg * 8] = o;
        }
    }
    __syncthreads();

    // ---- phase 2: MFMA 16x256; A broadcast from Zsm, B direct from Wt ----
    const int quad = lane >> 4;
    const int l16 = lane & 15;
    const int n0 = wave * 64;
    const u16* Bb = Wt + (size_t)(n0 + l16) * HD + quad * 8;

    f32x4 acc2[4];
#pragma unroll
    for (int j = 0; j < 4; ++j) acc2[j] = (f32x4){0.f, 0.f, 0.f, 0.f};

#pragma unroll
    for (int k0 = 0; k0 < HD; k0 += 32) {
        short8 a = *(const short8*)&Zsm[l16][k0 + quad * 8];
        short8 b[4];
#pragma unroll
        for (int j = 0; j < 4; ++j) b[j] = *(const short8*)&Bb[(size_t)j * 16 * HD + k0];
#pragma unroll
        for (int j = 0; j < 4; ++j)
            acc2[j] = __builtin_amdgcn_mfma_f32_16x16x32_bf16(a, b[j], acc2[j], 0, 0, 0);
    }

    float bw[4];
#pragma unroll
    for (int j = 0; j < 4; ++j) bw[j] = bias[n0 + j * 16 + l16];
#pragma unroll
    for (int r = 0; r < 4; ++r) {
        int m = m0 + quad * 4 + r;
        float d = scaleOut ? dinv[m] : 1.0f;
#pragma unroll
        for (int j = 0; j < 4; ++j) {
            int n = n0 + j * 16 + l16;
            float val = fmaxf(acc2[j][r] + bw[j], 0.f) * d;
            O[(size_t)m * HD + n] = f2bf(val);
        }
    }
}

// ---------------- fused pool + head ----------------
__global__ __launch_bounds__(256) void k_poolout(const u16* __restrict__ h,
                                                 const int* __restrict__ gstart,
                                                 const float* __restrict__ Wout,
                                                 const float* __restrict__ bout,
                                                 float* __restrict__ out) {
    int g = blockIdx.x;
    int t = threadIdx.x;
    __shared__ float pooled[HD];
    __shared__ float part[NC][16];
    __shared__ int s_se[2];
    if (t == 0) {
        int st = gstart[g];
        int en = NN;
        for (int gg = g + 1; gg < NG; ++gg) en = min(en, gstart[gg]);
        s_se[0] = st; s_se[1] = en;
    }
    __syncthreads();
    int st = s_se[0], en = s_se[1];
    float a0 = 0.f, a1 = 0.f, a2 = 0.f, a3 = 0.f;
    int n = st;
    for (; n + 4 <= en; n += 4) {
        a0 += bf2f(h[(size_t)n * HD + t]);
        a1 += bf2f(h[(size_t)(n + 1) * HD + t]);
        a2 += bf2f(h[(size_t)(n + 2) * HD + t]);
        a3 += bf2f(h[(size_t)(n + 3) * HD + t]);
    }
    for (; n < en; ++n) a0 += bf2f(h[(size_t)n * HD + t]);
    float inv = 1.0f / (float)max(en - st, 1);
    pooled[t] = (a0 + a1 + a2 + a3) * inv;
    __syncthreads();
    if (t < NC * 16) {
        int c = t >> 4, l16 = t & 15;
        float s = 0.f;
        for (int f = l16; f < HD; f += 16)
            s = fmaf(pooled[f], Wout[(size_t)f * NC + c], s);
        part[c][l16] = s;
    }
    __syncthreads();
    if (t < NC) {
        float s = 0.f;
#pragma unroll
        for (int k = 0; k < 16; ++k) s += part[t][k];
        out[(size_t)g * NC + t] = s + bout[t];
    }
}

extern "C" void kernel_launch(void* const* d_in, const int* in_sizes, int n_in,
                              void* d_out, int out_size, void* d_ws, size_t ws_size,
                              hipStream_t stream) {
    const float* x     = (const float*)d_in[0];
    const int*   ei    = (const int*)d_in[1];
    const int*   batch = (const int*)d_in[2];
    const float* Wl[5] = {(const float*)d_in[3], (const float*)d_in[5], (const float*)d_in[7],
                          (const float*)d_in[9], (const float*)d_in[11]};
    const float* bl[5] = {(const float*)d_in[4], (const float*)d_in[6], (const float*)d_in[8],
                          (const float*)d_in[10], (const float*)d_in[12]};
    const float* Wout = (const float*)d_in[13];
    const float* bout = (const float*)d_in[14];
    float* out = (float*)d_out;

    const int* row = ei;
    const int* col = ei + NE;

    char* p = (char*)d_ws;
    auto take = [&](size_t bytes) { char* q = p; p += (bytes + 255) & ~(size_t)255; return q; };
    float* dinv   = (float*)take(NN * 4);
    int*   degi   = (int*)take(NN * 4);
    int*   rowptr = (int*)take((NN + 1) * 4);
    int*   cursor = (int*)take(NN * 4);
    int*   bsum   = (int*)take(NB * 4);
    int*   ebuf   = (int*)take(NE * 4);
    int*   gstart = (int*)take(NG * 4);
    u16*   Wt[5];
    for (int l = 0; l < 5; ++l) Wt[l] = (u16*)take((size_t)HD * HD * 2);
    u16*   B1     = (u16*)take((size_t)NN * HD * 2);
    u16*   B2     = (u16*)take((size_t)NN * HD * 2);

    hipMemsetAsync(degi, 0, NN * 4, stream);
    hipMemsetAsync(gstart, 0x7F, NG * 4, stream);   // sentinel > NN
    k_deg<<<(NE + 255) / 256, 256, 0, stream>>>(col, degi, batch, gstart);
    k_scan1<<<NB, 256, 0, stream>>>(degi, rowptr, bsum);
    k_scan3<<<(NN * FIN / 4 + 255) / 256, 256, 0, stream>>>(degi, bsum, rowptr, cursor, dinv, x, B1);
    k_fill<<<(NE + 255) / 256, 256, 0, stream>>>(row, col, cursor, ebuf);
    dim3 tGrid(8, 8, 5);
    k_trans<<<tGrid, 256, 0, stream>>>(Wl[0], Wl[1], Wl[2], Wl[3], Wl[4],
                                       Wt[0], Wt[1], Wt[2], Wt[3], Wt[4]);

    // layer 1: split (64-wide aggregation + r10 LDS mm)
    k_gather64<<<(NN + 3) / 4, 256, 0, stream>>>(B1, rowptr, ebuf, dinv, B2);
    k_mm<<<(NN + 63) / 64, 256, 0, stream>>>(B2, Wt[0], bl[0], dinv, B1, FIN, 1);
    // layers 2..5: fused M=16 gather+MFMA, ping-pong B1 <-> B2
    const int fgrid = NN / 16;   // 1250
    k_flayer16<<<fgrid, 256, 0, stream>>>(B1, rowptr, ebuf, dinv, Wt[1], bl[1], B2, 1);
    k_flayer16<<<fgrid, 256, 0, stream>>>(B2, rowptr, ebuf, dinv, Wt[2], bl[2], B1, 1);
    k_flayer16<<<fgrid, 256, 0, stream>>>(B1, rowptr, ebuf, dinv, Wt[3], bl[3], B2, 1);
    k_flayer16<<<fgrid, 256, 0, stream>>>(B2, rowptr, ebuf, dinv, Wt[4], bl[4], B1, 0);

    k_poolout<<<NG, 256, 0, stream>>>(B1, gstart, Wout, bout, out);
}

// Round 15
// 347.677 us; speedup vs baseline: 1.1058x; 1.0808x over previous
//
#include <hip/hip_runtime.h>

#define NN 20000
#define NE 320000
#define FIN 64
#define HD 256
#define NC 10
#define NG 64
#define NB ((NN + 255) / 256)      // 79 scan blocks
#define EBMAX (NE + 15 * NN + 16)  // padded CSR upper bound (u16 slots)

typedef unsigned short u16;
typedef unsigned int u32;
typedef __attribute__((ext_vector_type(8))) short short8;   // 8 bf16 (4 VGPRs)
typedef __attribute__((ext_vector_type(4))) float f32x4;    // 4 fp32 acc

__device__ __forceinline__ float bf2f(u16 u) {
    union { u32 i; float f; } v; v.i = ((u32)u) << 16; return v.f;
}
__device__ __forceinline__ u16 f2bf(float f) {
    union { float f; u32 i; } v; v.f = f;
    u32 r = v.i + 0x7fffu + ((v.i >> 16) & 1u);   // RNE
    return (u16)(r >> 16);
}

// ---------------- degree count + graph bounds (degi zeroed by memset) ------
__global__ void k_deg(const int* __restrict__ col, int* __restrict__ degi,
                      const int* __restrict__ batch, int* __restrict__ gstart) {
    int i = blockIdx.x * 256 + threadIdx.x;
    if (i < NE) atomicAdd(&degi[col[i]], 1);
    if (i < NN) {
        int b = batch[i];
        int prev = (i == 0) ? -1 : batch[i - 1];
        if (b != prev) gstart[b] = i;
    }
}

// ---------------- pad-fill ebuf with sentinel NN (0x4E20) ------------------
__global__ void k_pad(u32* __restrict__ ebuf32) {
    int i = blockIdx.x * 256 + threadIdx.x;
    if (i < EBMAX / 2) ebuf32[i] = 0x4E204E20u;   // two u16 = NN, NN
}

// ---------------- scan stage 1: padded-degree block scan + block sums ------
__global__ __launch_bounds__(256) void k_scan1(const int* __restrict__ degi,
                                               int* __restrict__ rowptr,
                                               int* __restrict__ bsum) {
    int t = threadIdx.x;
    int i = blockIdx.x * 256 + t;
    int v = (i < NN) ? ((degi[i] + 15) & ~15) : 0;   // padded degree
    int lane = t & 63, wid = t >> 6;
    int x = v;
#pragma unroll
    for (int off = 1; off < 64; off <<= 1) {
        int y = __shfl_up(x, off);
        if (lane >= off) x += y;
    }
    __shared__ int ws[4];
    if (lane == 63) ws[wid] = x;
    __syncthreads();
    int woff = 0;
    for (int w = 0; w < wid; ++w) woff += ws[w];
    if (i < NN) rowptr[i] = woff + x - v;
    if (t == 255) bsum[blockIdx.x] = woff + x;
}

// ---------------- scan 2+3 fused: fixup + cursor + dinv + u0 (+zero row NN)
__global__ void k_scan3(const int* __restrict__ degi, const int* __restrict__ bsum,
                        int* __restrict__ rowptr, int* __restrict__ cursor,
                        float* __restrict__ dinv,
                        const float* __restrict__ x, u16* __restrict__ u0) {
    __shared__ int pref[NB];
    if (threadIdx.x < NB) pref[threadIdx.x] = bsum[threadIdx.x];
    __syncthreads();
    if (threadIdx.x == 0) {
        int run = 0;
        for (int k = 0; k < NB; ++k) { int t = pref[k]; pref[k] = run; run += t; }
    }
    __syncthreads();
    int i = blockIdx.x * 256 + threadIdx.x;
    if (i < NN) {
        int dg = degi[i];
        int rp = rowptr[i] + pref[i >> 8];
        rowptr[i] = rp;
        cursor[i] = rp;
        dinv[i] = rsqrtf((float)(1 + dg));
        if (i == NN - 1) rowptr[NN] = rp + ((dg + 15) & ~15);
    }
    if (i < NN * FIN / 4) {
        int node = i >> 4;
        float d = rsqrtf((float)(1 + degi[node]));
        float4 v = *(const float4*)&x[(size_t)i * 4];
        u32 lo = (u32)f2bf(v.x * d) | ((u32)f2bf(v.y * d) << 16);
        u32 hi = (u32)f2bf(v.z * d) | ((u32)f2bf(v.w * d) << 16);
        *(uint2*)&u0[(size_t)i * 4] = make_uint2(lo, hi);
    }
    if (blockIdx.x == 0 && threadIdx.x < FIN) u0[(size_t)NN * FIN + threadIdx.x] = 0;  // dummy row
}

// ---------------- fill CSR buckets (u16 payload) ----------------
__global__ void k_fill(const int* __restrict__ row, const int* __restrict__ col,
                       int* __restrict__ cursor, u16* __restrict__ ebuf) {
    int e = blockIdx.x * 256 + threadIdx.x;
    if (e < NE) {
        int c = col[e];
        int pos = atomicAdd(&cursor[c], 1);
        ebuf[pos] = (u16)row[e];
    }
}

// ---------------- LDS-tiled transpose+cast of all 5 W ----------------
__global__ __launch_bounds__(256) void k_trans(const float* __restrict__ W0, const float* __restrict__ W1,
                                               const float* __restrict__ W2, const float* __restrict__ W3,
                                               const float* __restrict__ W4,
                                               u16* __restrict__ T0, u16* __restrict__ T1,
                                               u16* __restrict__ T2, u16* __restrict__ T3,
                                               u16* __restrict__ T4) {
    int l = blockIdx.z;
    const float* W = (l == 0) ? W0 : (l == 1) ? W1 : (l == 2) ? W2 : (l == 3) ? W3 : W4;
    u16* T = (l == 0) ? T0 : (l == 1) ? T1 : (l == 2) ? T2 : (l == 3) ? T3 : T4;
    int K = (l == 0) ? FIN : HD;
    int k0 = blockIdx.x * 32;
    if (k0 >= K) return;
    int n0 = blockIdx.y * 32;
    __shared__ float tile[32][33];
    int tx = threadIdx.x & 31, ty = threadIdx.x >> 5;
#pragma unroll
    for (int r = 0; r < 32; r += 8)
        tile[ty + r][tx] = W[(size_t)(k0 + ty + r) * HD + n0 + tx];
    __syncthreads();
#pragma unroll
    for (int r = 0; r < 32; r += 8)
        T[(size_t)(n0 + ty + r) * K + k0 + tx] = f2bf(tile[tx][ty + r]);
}

// ---------------- gather, half-split, padded CSR: guard-free inner loop ----
__global__ __launch_bounds__(256) void k_gatherh(const u16* __restrict__ U,
                                                 const int* __restrict__ rowptr,
                                                 const u16* __restrict__ ebuf,
                                                 const float* __restrict__ dinv,
                                                 u16* __restrict__ Z) {
    int b = blockIdx.x;
    int half = b & 1;
    int tile = b >> 1;
    int n = tile * 4 + (threadIdx.x >> 6);
    if (n >= NN) return;
    int lane = threadIdx.x & 63;
    int grp = lane >> 4;            // 0..3
    int seg = lane & 15;            // 16-B segment within the 128-feature half
    int fbase = half * 128 + seg * 8;
    int s = rowptr[n], e = rowptr[n + 1];   // padded: multiple of 16 slots
    float acc[8];
    if (grp == 0) {                 // self-loop
        uint4 v = *(const uint4*)&U[(size_t)n * HD + fbase];
        acc[0] = bf2f((u16)(v.x & 0xffff)); acc[1] = bf2f((u16)(v.x >> 16));
        acc[2] = bf2f((u16)(v.y & 0xffff)); acc[3] = bf2f((u16)(v.y >> 16));
        acc[4] = bf2f((u16)(v.z & 0xffff)); acc[5] = bf2f((u16)(v.z >> 16));
        acc[6] = bf2f((u16)(v.w & 0xffff)); acc[7] = bf2f((u16)(v.w >> 16));
    } else {
#pragma unroll
        for (int k = 0; k < 8; ++k) acc[k] = 0.f;
    }
    for (int j = s; j < e; j += 16) {
        int myid = (lane < 16) ? (int)ebuf[j + lane] : 0;   // pad slots hold NN (zero row)
        uint4 v[4];
#pragma unroll
        for (int k = 0; k < 4; ++k) {
            int r = __shfl(myid, grp * 4 + k);
            v[k] = *(const uint4*)&U[(size_t)r * HD + fbase];
        }
#pragma unroll
        for (int k = 0; k < 4; ++k) {
            acc[0] += bf2f((u16)(v[k].x & 0xffff)); acc[1] += bf2f((u16)(v[k].x >> 16));
            acc[2] += bf2f((u16)(v[k].y & 0xffff)); acc[3] += bf2f((u16)(v[k].y >> 16));
            acc[4] += bf2f((u16)(v[k].z & 0xffff)); acc[5] += bf2f((u16)(v[k].z >> 16));
            acc[6] += bf2f((u16)(v[k].w & 0xffff)); acc[7] += bf2f((u16)(v[k].w >> 16));
        }
    }
#pragma unroll
    for (int k = 0; k < 8; ++k) {
        acc[k] += __shfl_xor(acc[k], 16);
        acc[k] += __shfl_xor(acc[k], 32);
    }
    if (grp == 0) {
        float d = dinv[n];
        uint4 o;
        o.x = (u32)f2bf(acc[0] * d) | ((u32)f2bf(acc[1] * d) << 16);
        o.y = (u32)f2bf(acc[2] * d) | ((u32)f2bf(acc[3] * d) << 16);
        o.z = (u32)f2bf(acc[4] * d) | ((u32)f2bf(acc[5] * d) << 16);
        o.w = (u32)f2bf(acc[6] * d) | ((u32)f2bf(acc[7] * d) << 16);
        *(uint4*)&Z[(size_t)n * HD + fbase] = o;
    }
}

// ---------------- gather 64-wide (layer 1), padded CSR: guard-free ---------
__global__ __launch_bounds__(256) void k_gather64(const u16* __restrict__ U,
                                                  const int* __restrict__ rowptr,
                                                  const u16* __restrict__ ebuf,
                                                  const float* __restrict__ dinv,
                                                  u16* __restrict__ Z) {
    int n = blockIdx.x * 4 + (threadIdx.x >> 6);
    if (n >= NN) return;
    int lane = threadIdx.x & 63;
    int grp = lane >> 3;            // 0..7
    int seg = lane & 7;             // 16-B feature segment
    int s = rowptr[n], e = rowptr[n + 1];
    float acc[8];
    if (grp == 0) {
        uint4 v = *(const uint4*)&U[(size_t)n * FIN + seg * 8];
        acc[0] = bf2f((u16)(v.x & 0xffff)); acc[1] = bf2f((u16)(v.x >> 16));
        acc[2] = bf2f((u16)(v.y & 0xffff)); acc[3] = bf2f((u16)(v.y >> 16));
        acc[4] = bf2f((u16)(v.z & 0xffff)); acc[5] = bf2f((u16)(v.z >> 16));
        acc[6] = bf2f((u16)(v.w & 0xffff)); acc[7] = bf2f((u16)(v.w >> 16));
    } else {
#pragma unroll
        for (int k = 0; k < 8; ++k) acc[k] = 0.f;
    }
    for (int j = s; j < e; j += 16) {
        int r0 = (int)ebuf[j + grp];
        int r1 = (int)ebuf[j + 8 + grp];
        uint4 v0 = *(const uint4*)&U[(size_t)r0 * FIN + seg * 8];
        uint4 v1 = *(const uint4*)&U[(size_t)r1 * FIN + seg * 8];
        acc[0] += bf2f((u16)(v0.x & 0xffff)); acc[1] += bf2f((u16)(v0.x >> 16));
        acc[2] += bf2f((u16)(v0.y & 0xffff)); acc[3] += bf2f((u16)(v0.y >> 16));
        acc[4] += bf2f((u16)(v0.z & 0xffff)); acc[5] += bf2f((u16)(v0.z >> 16));
        acc[6] += bf2f((u16)(v0.w & 0xffff)); acc[7] += bf2f((u16)(v0.w >> 16));
        acc[0] += bf2f((u16)(v1.x & 0xffff)); acc[1] += bf2f((u16)(v1.x >> 16));
        acc[2] += bf2f((u16)(v1.y & 0xffff)); acc[3] += bf2f((u16)(v1.y >> 16));
        acc[4] += bf2f((u16)(v1.z & 0xffff)); acc[5] += bf2f((u16)(v1.z >> 16));
        acc[6] += bf2f((u16)(v1.w & 0xffff)); acc[7] += bf2f((u16)(v1.w >> 16));
    }
#pragma unroll
    for (int off = 8; off < 64; off <<= 1)
#pragma unroll
        for (int k = 0; k < 8; ++k) acc[k] += __shfl_xor(acc[k], off);
    if (grp == 0) {
        float d = dinv[n];
        uint4 o;
        o.x = (u32)f2bf(acc[0] * d) | ((u32)f2bf(acc[1] * d) << 16);
        o.y = (u32)f2bf(acc[2] * d) | ((u32)f2bf(acc[3] * d) << 16);
        o.z = (u32)f2bf(acc[4] * d) | ((u32)f2bf(acc[5] * d) << 16);
        o.w = (u32)f2bf(acc[6] * d) | ((u32)f2bf(acc[7] * d) << 16);
        *(uint4*)&Z[(size_t)n * FIN + seg * 8] = o;
    }
}

// ---------------- MFMA matmul (r10 LDS version) + dummy-row zeroing --------
__global__ __launch_bounds__(256) void k_mm(const u16* __restrict__ A,
                                            const u16* __restrict__ Wt,
                                            const float* __restrict__ bias,
                                            const float* __restrict__ dinv,
                                            u16* __restrict__ O,
                                            int K, int scaleOut) {
    __shared__ u16 Asm[64][40];
    __shared__ u16 Bsm[256][40];
    __shared__ float bs[HD];
    const int m0 = blockIdx.x * 64;
    const int t = threadIdx.x;
    const int wave = t >> 6;
    const int lane = t & 63;
    const int quad = lane >> 4;
    const int l16 = lane & 15;
    const int n0 = wave * 64;
    bs[t] = bias[t];
    if (blockIdx.x == 0) O[(size_t)NN * HD + t] = 0;   // keep dummy row zero for next gather

    f32x4 acc[4][4];
#pragma unroll
    for (int i = 0; i < 4; ++i)
#pragma unroll
        for (int j = 0; j < 4; ++j) acc[i][j] = (f32x4){0.f, 0.f, 0.f, 0.f};

    for (int k0 = 0; k0 < K; k0 += 32) {
        {
            int row = t >> 2, seg = t & 3;
            int gm = m0 + row;
            float4 v = make_float4(0.f, 0.f, 0.f, 0.f);
            if (gm < NN) v = *(const float4*)&A[(size_t)gm * K + k0 + seg * 8];
            *(float4*)&Asm[row][seg * 8] = v;
        }
        {
#pragma unroll
            for (int j = 0; j < 4; ++j) {
                float4 v = *(const float4*)&Wt[(size_t)t * K + k0 + j * 8];
                *(float4*)&Bsm[t][j * 8] = v;
            }
        }
        __syncthreads();
        short8 a[4], b[4];
#pragma unroll
        for (int i = 0; i < 4; ++i) a[i] = *(const short8*)&Asm[i * 16 + l16][quad * 8];
#pragma unroll
        for (int j = 0; j < 4; ++j) b[j] = *(const short8*)&Bsm[n0 + j * 16 + l16][quad * 8];
#pragma unroll
        for (int i = 0; i < 4; ++i)
#pragma unroll
            for (int j = 0; j < 4; ++j)
                acc[i][j] = __builtin_amdgcn_mfma_f32_16x16x32_bf16(a[i], b[j], acc[i][j], 0, 0, 0);
        __syncthreads();
    }
#pragma unroll
    for (int i = 0; i < 4; ++i) {
#pragma unroll
        for (int r = 0; r < 4; ++r) {
            int m = m0 + i * 16 + quad * 4 + r;
            if (m >= NN) continue;
            float d = scaleOut ? dinv[m] : 1.0f;
#pragma unroll
            for (int j = 0; j < 4; ++j) {
                int n = n0 + j * 16 + l16;
                float val = fmaxf(acc[i][j][r] + bs[n], 0.f) * d;
                O[(size_t)m * HD + n] = f2bf(val);
            }
        }
    }
}

// ---------------- fused pool + head ----------------
__global__ __launch_bounds__(256) void k_poolout(const u16* __restrict__ h,
                                                 const int* __restrict__ gstart,
                                                 const float* __restrict__ Wout,
                                                 const float* __restrict__ bout,
                                                 float* __restrict__ out) {
    int g = blockIdx.x;
    int t = threadIdx.x;
    __shared__ float pooled[HD];
    __shared__ float part[NC][16];
    __shared__ int s_se[2];
    if (t == 0) {
        int st = gstart[g];
        int en = NN;
        for (int gg = g + 1; gg < NG; ++gg) en = min(en, gstart[gg]);
        s_se[0] = st; s_se[1] = en;
    }
    __syncthreads();
    int st = s_se[0], en = s_se[1];
    float a0 = 0.f, a1 = 0.f, a2 = 0.f, a3 = 0.f;
    int n = st;
    for (; n + 4 <= en; n += 4) {
        a0 += bf2f(h[(size_t)n * HD + t]);
        a1 += bf2f(h[(size_t)(n + 1) * HD + t]);
        a2 += bf2f(h[(size_t)(n + 2) * HD + t]);
        a3 += bf2f(h[(size_t)(n + 3) * HD + t]);
    }
    for (; n < en; ++n) a0 += bf2f(h[(size_t)n * HD + t]);
    float inv = 1.0f / (float)max(en - st, 1);
    pooled[t] = (a0 + a1 + a2 + a3) * inv;
    __syncthreads();
    if (t < NC * 16) {
        int c = t >> 4, l16 = t & 15;
        float s = 0.f;
        for (int f = l16; f < HD; f += 16)
            s = fmaf(pooled[f], Wout[(size_t)f * NC + c], s);
        part[c][l16] = s;
    }
    __syncthreads();
    if (t < NC) {
        float s = 0.f;
#pragma unroll
        for (int k = 0; k < 16; ++k) s += part[t][k];
        out[(size_t)g * NC + t] = s + bout[t];
    }
}

extern "C" void kernel_launch(void* const* d_in, const int* in_sizes, int n_in,
                              void* d_out, int out_size, void* d_ws, size_t ws_size,
                              hipStream_t stream) {
    const float* x     = (const float*)d_in[0];
    const int*   ei    = (const int*)d_in[1];
    const int*   batch = (const int*)d_in[2];
    const float* Wl[5] = {(const float*)d_in[3], (const float*)d_in[5], (const float*)d_in[7],
                          (const float*)d_in[9], (const float*)d_in[11]};
    const float* bl[5] = {(const float*)d_in[4], (const float*)d_in[6], (const float*)d_in[8],
                          (const float*)d_in[10], (const float*)d_in[12]};
    const float* Wout = (const float*)d_in[13];
    const float* bout = (const float*)d_in[14];
    float* out = (float*)d_out;

    const int* row = ei;
    const int* col = ei + NE;

    char* p = (char*)d_ws;
    auto take = [&](size_t bytes) { char* q = p; p += (bytes + 255) & ~(size_t)255; return q; };
    float* dinv   = (float*)take(NN * 4);
    int*   degi   = (int*)take(NN * 4);
    int*   rowptr = (int*)take((NN + 1) * 4);
    int*   cursor = (int*)take(NN * 4);
    int*   bsum   = (int*)take(NB * 4);
    u16*   ebuf   = (u16*)take(EBMAX * 2);
    int*   gstart = (int*)take(NG * 4);
    u16*   Wt[5];
    for (int l = 0; l < 5; ++l) Wt[l] = (u16*)take((size_t)HD * HD * 2);
    u16*   B1     = (u16*)take((size_t)(NN + 1) * HD * 2);   // +1 dummy zero row
    u16*   B2     = (u16*)take((size_t)(NN + 1) * HD * 2);

    hipMemsetAsync(degi, 0, NN * 4, stream);
    hipMemsetAsync(gstart, 0x7F, NG * 4, stream);   // sentinel > NN
    k_deg<<<(NE + 255) / 256, 256, 0, stream>>>(col, degi, batch, gstart);
    k_pad<<<(EBMAX / 2 + 255) / 256, 256, 0, stream>>>((u32*)ebuf);
    k_scan1<<<NB, 256, 0, stream>>>(degi, rowptr, bsum);
    k_scan3<<<(NN * FIN / 4 + 255) / 256, 256, 0, stream>>>(degi, bsum, rowptr, cursor, dinv, x, B1);
    k_fill<<<(NE + 255) / 256, 256, 0, stream>>>(row, col, cursor, ebuf);
    dim3 tGrid(8, 8, 5);
    k_trans<<<tGrid, 256, 0, stream>>>(Wl[0], Wl[1], Wl[2], Wl[3], Wl[4],
                                       Wt[0], Wt[1], Wt[2], Wt[3], Wt[4]);

    // layer 1 (64-wide aggregation first)
    k_gather64<<<(NN + 3) / 4, 256, 0, stream>>>(B1, rowptr, ebuf, dinv, B2);
    k_mm<<<(NN + 63) / 64, 256, 0, stream>>>(B2, Wt[0], bl[0], dinv, B1, FIN, 1);
    // layers 2..5: half-split gather + LDS mm (r10 structure)
    const int gGrid = 2 * ((NN + 3) / 4);
    for (int l = 1; l < 5; ++l) {
        k_gatherh<<<gGrid, 256, 0, stream>>>(B1, rowptr, ebuf, dinv, B2);
        k_mm<<<(NN + 63) / 64, 256, 0, stream>>>(B2, Wt[l], bl[l], dinv, B1, HD, (l < 4) ? 1 : 0);
    }

    k_poolout<<<NG, 256, 0, stream>>>(B1, gstart, Wout, bout, out);
}